// Round 6
// baseline (291.999 us; speedup 1.0000x reference)
//
#include <hip/hip_runtime.h>
#include <hip/hip_fp16.h>

#define CIN   32
#define COUT  64
#define TT    8
#define HH    56
#define WW    56
#define KK    27
#define SP    (TT * HH * WW)   // 25088
#define NB    2
#define NBLK  784              // (NB*SP)/64

typedef __attribute__((ext_vector_type(8)))  _Float16 half8;
typedef __attribute__((ext_vector_type(16))) float    f32x16;

// d_ws layout
#define WF_OFF   0                        // weight A-frags: 110,592 B
#define XTH_OFF  (128 << 10)              // xTh fp16 channel-last: 3,211,264 B
#define CNT_OFF  (XTH_OFF + 3211264)     // 4 B arrive counter (memset to 0 on stream)

__global__ __launch_bounds__(256, 4) void fused_kernel(const float* __restrict__ x,
                                                       const float* __restrict__ off,
                                                       const float* __restrict__ w,
                                                       const float* __restrict__ bias,
                                                       __half* __restrict__ xTh,
                                                       __half* __restrict__ wf,
                                                       unsigned int* __restrict__ cnt,
                                                       float* __restrict__ out) {
    // shared buffer reused: phase 1 = float sm[32][65] (8320 B); phase 2 = vtB (8192 B)
    __shared__ __align__(16) char smem[8448];
    float (*sm)[65] = reinterpret_cast<float(*)[65]>(smem);
    // vtB[buf][pos_tile][mfma_m][fraglane][8 fp16]
    __half (*vtB)[2][2][64][8] = reinterpret_cast<__half(*)[2][2][64][8]>(smem);

    const int b = blockIdx.x;
    const int t = threadIdx.x;

    // ================= phase 1: prep (x -> fp16 channel-last; w -> A-frags) ======
    {
        const int s0p = b * 64, np = s0p / SP, sp0 = s0p % SP;
#pragma unroll
        for (int it = 0; it < 8; ++it) {
            const int idx = it * 256 + t, c = idx >> 6, l = idx & 63;
            sm[c][l] = x[((size_t)np * CIN + c) * SP + sp0 + l];
        }
        __syncthreads();
#pragma unroll
        for (int it = 0; it < 4; ++it) {
            const int idx = it * 256 + t, l = idx >> 4, cp = idx & 15;
            ((__half2*)xTh)[((size_t)np * SP + sp0 + l) * (CIN / 2) + cp] =
                __floats2half2_rn(sm[2 * cp][l], sm[2 * cp + 1][l]);
        }
        if (b < KK) {  // blocks 0..26 also pack tap b's weight fragments
            const int k = b;
#pragma unroll
            for (int it = 0; it < 8; ++it) {
                const int idx  = it * 256 + t;  // [ct(2)][m(2)][lane(64)][j(8)]
                const int j    = idx & 7;
                const int lane = (idx >> 3) & 63;
                const int m    = (idx >> 9) & 1;
                const int ct2  = (idx >> 10) & 1;
                const int co   = ct2 * 32 + (lane & 31);
                const int c    = m * 16 + (lane >> 5) * 8 + j;
                wf[((((size_t)k * 2 + ct2) * 2 + m) * 64 + lane) * 8 + j] =
                    __float2half(w[((size_t)co * CIN + c) * KK + k]);
            }
        }
    }

    // ================= device-wide barrier (all 784 blocks co-resident) ==========
    __threadfence();          // agent-scope release: drain + L2 writeback
    __syncthreads();
    if (t == 0) {
        __hip_atomic_fetch_add(cnt, 1u, __ATOMIC_ACQ_REL, __HIP_MEMORY_SCOPE_AGENT);
        while (__hip_atomic_load(cnt, __ATOMIC_ACQUIRE, __HIP_MEMORY_SCOPE_AGENT) < NBLK)
            __builtin_amdgcn_s_sleep(2);
    }
    __syncthreads();

    // ================= phase 2: deformable conv main loop ========================
    const int lane = t & 63;
    const int wv   = t >> 6;
    const int cg   = wv;                                        // interp: 8-ch group
    const int ct   = __builtin_amdgcn_readfirstlane(wv & 1);    // gemm: co tile
    const int pt   = __builtin_amdgcn_readfirstlane(wv >> 1);   // gemm: pos tile

    // XCD-aware swizzle (bijective on 784; 392*64 == SP so no batch crossing)
    const int sb  = (b & 7) * 98 + (b >> 3);
    const int s0  = sb * 64;
    const int n   = s0 / SP;
    const int spb = s0 % SP;

    const int sp = spb + lane;
    const int to = sp / (HH * WW);
    const int hw = sp % (HH * WW);
    const int ho = hw / WW;
    const int wo = hw % WW;

    f32x16 acc;
#pragma unroll
    for (int i = 0; i < 16; ++i) acc[i] = 0.f;

    const __half* xn   = xTh + (size_t)n * SP * CIN;
    const float*  offn = off + (size_t)n * (3 * KK) * SP + sp;

    int   a[8];
    float cw[8];
    float4 g[8];

    // tap-address helper
    auto comp_tap = [&](int k, float o0, float o1, float o2) {
        const int kt  = k / 9;
        const int khh = (k / 3) % 3;
        const int kww = k % 3;
        const float pt_ = (float)(to - 1 + kt)  + o0;
        const float ph_ = (float)(ho - 1 + khh) + o1;
        const float pw_ = (float)(wo - 1 + kww) + o2;
        const float ft = floorf(pt_), fh = floorf(ph_), fw = floorf(pw_);
        const float lt = pt_ - ft, lh = ph_ - fh, lw = pw_ - fw;
        const int t0 = (int)ft, h0 = (int)fh, w0 = (int)fw;
        float awt[2], awh[2], aww[2];
        int   it2[2], ih2[2], iw2[2];
        const int t1 = t0 + 1, h1 = h0 + 1, w1 = w0 + 1;
        awt[0] = (t0 >= 0 && t0 < TT) ? (1.f - lt) : 0.f;
        awt[1] = (t1 >= 0 && t1 < TT) ? lt : 0.f;
        it2[0] = min(max(t0, 0), TT - 1);  it2[1] = min(max(t1, 0), TT - 1);
        awh[0] = (h0 >= 0 && h0 < HH) ? (1.f - lh) : 0.f;
        awh[1] = (h1 >= 0 && h1 < HH) ? lh : 0.f;
        ih2[0] = min(max(h0, 0), HH - 1);  ih2[1] = min(max(h1, 0), HH - 1);
        aww[0] = (w0 >= 0 && w0 < WW) ? (1.f - lw) : 0.f;
        aww[1] = (w1 >= 0 && w1 < WW) ? lw : 0.f;
        iw2[0] = min(max(w0, 0), WW - 1);  iw2[1] = min(max(w1, 0), WW - 1);
#pragma unroll
        for (int ci = 0; ci < 8; ++ci) {
            const int i0 = ci >> 2, i1 = (ci >> 1) & 1, i2 = ci & 1;
            a[ci]  = (it2[i0] * HH + ih2[i1]) * WW + iw2[i2];
            cw[ci] = awt[i0] * awh[i1] * aww[i2];
        }
    };

    // prologue: tap 0 addresses + gathers + A-frags; offsets for tap 1 prefetched
    comp_tap(0, offn[0], offn[SP], offn[2 * SP]);
#pragma unroll
    for (int ci = 0; ci < 8; ++ci)
        g[ci] = *(const float4*)(xn + (size_t)a[ci] * CIN + cg * 8);
    half8 af0 = *(const half8*)(wf + ((((size_t)0 * 2 + ct) * 2 + 0) * 64 + lane) * 8);
    half8 af1 = *(const half8*)(wf + ((((size_t)0 * 2 + ct) * 2 + 1) * 64 + lane) * 8);
    float oB0 = offn[3 * SP], oB1 = offn[4 * SP], oB2 = offn[5 * SP];

    for (int k = 0; k < KK; ++k) {
        // ---- consume tap k's gathers (issued one iteration ago -> latency hidden)
        __half2 vacc[4];
#pragma unroll
        for (int j = 0; j < 4; ++j) vacc[j] = __floats2half2_rn(0.f, 0.f);
#pragma unroll
        for (int ci = 0; ci < 8; ++ci) {
            const __half2* uh = (const __half2*)&g[ci];
            const __half2 cw2 = __float2half2_rn(cw[ci]);
            vacc[0] = __hfma2(cw2, uh[0], vacc[0]);
            vacc[1] = __hfma2(cw2, uh[1], vacc[1]);
            vacc[2] = __hfma2(cw2, uh[2], vacc[2]);
            vacc[3] = __hfma2(cw2, uh[3], vacc[3]);
        }

        // ---- prep tap k+1: addresses, issue gathers (stay in flight past barrier)
        if (k + 1 < KK) {
            comp_tap(k + 1, oB0, oB1, oB2);
            const int k2 = (k + 2 < KK) ? (k + 2) : (KK - 1);
            oB0 = offn[(k2 * 3 + 0) * SP];
            oB1 = offn[(k2 * 3 + 1) * SP];
            oB2 = offn[(k2 * 3 + 2) * SP];
#pragma unroll
            for (int ci = 0; ci < 8; ++ci)
                g[ci] = *(const float4*)(xn + (size_t)a[ci] * CIN + cg * 8);
        }

        // ---- publish tap k's B-fragment (one b128, contiguous per wave)
        *(float4*)&vtB[k & 1][lane >> 5][cg >> 1][(cg & 1) * 32 + (lane & 31)][0] =
            *(const float4*)vacc;

        // LDS-only barrier: no vmcnt drain, global gathers stay in flight
        __builtin_amdgcn_fence(__ATOMIC_RELEASE, "workgroup", "local");
        __builtin_amdgcn_s_barrier();
        __builtin_amdgcn_fence(__ATOMIC_ACQUIRE, "workgroup", "local");

        // ---- GEMM tap k: wave's 32x32 C-tile, K=32 as 2 MFMAs
        const half8 b0 = *(const half8*)&vtB[k & 1][pt][0][lane][0];
        const half8 b1 = *(const half8*)&vtB[k & 1][pt][1][lane][0];
        acc = __builtin_amdgcn_mfma_f32_32x32x16_f16(af0, b0, acc, 0, 0, 0);
        acc = __builtin_amdgcn_mfma_f32_32x32x16_f16(af1, b1, acc, 0, 0, 0);

        if (k + 1 < KK) {  // prefetch next tap's A-frags (L2-resident, hidden)
            af0 = *(const half8*)(wf + ((((size_t)(k + 1) * 2 + ct) * 2 + 0) * 64 + lane) * 8);
            af1 = *(const half8*)(wf + ((((size_t)(k + 1) * 2 + ct) * 2 + 1) * 64 + lane) * 8);
        }
    }

    // epilogue: HW-verified C/D map: col=lane&31, row=(reg&3)+8*(reg>>2)+4*(lane>>5)
#pragma unroll
    for (int r = 0; r < 16; ++r) {
        const int row = (r & 3) + 8 * (r >> 2) + 4 * (lane >> 5);
        const int co  = ct * 32 + row;
        const int pos = pt * 32 + (lane & 31);
        out[((size_t)n * COUT + co) * SP + spb + pos] = acc[r] + bias[co];
    }
}

extern "C" void kernel_launch(void* const* d_in, const int* in_sizes, int n_in,
                              void* d_out, int out_size, void* d_ws, size_t ws_size,
                              hipStream_t stream) {
    const float* x    = (const float*)d_in[0];
    const float* off  = (const float*)d_in[1];
    const float* w    = (const float*)d_in[2];
    const float* bias = (const float*)d_in[3];
    float* out        = (float*)d_out;

    __half* wf         = (__half*)((char*)d_ws + WF_OFF);
    __half* xTh        = (__half*)((char*)d_ws + XTH_OFF);
    unsigned int* cnt  = (unsigned int*)((char*)d_ws + CNT_OFF);

    hipMemsetAsync(cnt, 0, sizeof(unsigned int), stream);
    fused_kernel<<<NBLK, 256, 0, stream>>>(x, off, w, bias, xTh, wf, cnt, out);
}

// Round 7
// 160.900 us; speedup vs baseline: 1.8148x; 1.8148x over previous
//
#include <hip/hip_runtime.h>
#include <hip/hip_fp16.h>

#define CIN   32
#define COUT  64
#define TT    8
#define HH    56
#define WW    56
#define KK    27
#define SP    (TT * HH * WW)   // 25088
#define NB    2
#define NBLK  784              // (NB*SP)/64

typedef __attribute__((ext_vector_type(8))) _Float16 half8;
typedef __attribute__((ext_vector_type(4))) float    f32x4;

// d_ws layout
#define WF_OFF   0                    // weight A-frags (16x16x32): 110,592 B
#define XTH_OFF  (128 << 10)          // xTh fp16 channel-last: 3,211,264 B

// prep: blocks [0,784): x [N][C][SP] fp32 -> xTh [N][SP][C] fp16
//       blocks [784,811): weight -> 16x16x32 A-fragments
//       wf[k][ct][lane][j] = w[co = ct*16 + (lane&15)][c = (lane>>4)*8 + j][k]
__global__ __launch_bounds__(256) void prep_kernel(const float* __restrict__ x,
                                                   const float* __restrict__ w,
                                                   __half* __restrict__ xTh,
                                                   __half* __restrict__ wf) {
    const int b = blockIdx.x;
    const int t = threadIdx.x;
    if (b < NBLK) {
        __shared__ float sm[CIN][65];
        const int s0 = b * 64, n = s0 / SP, sp0 = s0 % SP;
#pragma unroll
        for (int it = 0; it < 8; ++it) {
            const int idx = it * 256 + t, c = idx >> 6, l = idx & 63;
            sm[c][l] = x[((size_t)n * CIN + c) * SP + sp0 + l];
        }
        __syncthreads();
#pragma unroll
        for (int it = 0; it < 4; ++it) {
            const int idx = it * 256 + t, l = idx >> 4, cp = idx & 15;
            ((__half2*)xTh)[((size_t)n * SP + sp0 + l) * (CIN / 2) + cp] =
                __floats2half2_rn(sm[2 * cp][l], sm[2 * cp + 1][l]);
        }
    } else {
        const int k = b - NBLK;        // 2048 elements: [ct(4)][lane(64)][j(8)]
#pragma unroll
        for (int it = 0; it < 8; ++it) {
            const int idx  = it * 256 + t;
            const int j    = idx & 7;
            const int lane = (idx >> 3) & 63;
            const int ct   = (idx >> 9) & 3;
            const int co   = ct * 16 + (lane & 15);
            const int c    = (lane >> 4) * 8 + j;
            wf[(((size_t)k * 4 + ct) * 64 + lane) * 8 + j] =
                __float2half(w[((size_t)co * CIN + c) * KK + k]);
        }
    }
}

// Barrier-free main kernel: wave = 16 positions x full Cout.
// Interp builds the 16x16x32 B-fragment directly in registers (no LDS).
__global__ __launch_bounds__(256, 3) void dconv3d_kernel(const __half* __restrict__ xTh,
                                                         const float* __restrict__ off,
                                                         const __half* __restrict__ wf,
                                                         const float* __restrict__ bias,
                                                         float* __restrict__ out) {
    const int lane = threadIdx.x & 63;
    const int wv   = threadIdx.x >> 6;
    const int posq = lane & 15;        // position within wave tile
    const int cg   = lane >> 4;        // channel quad: 8 channels cg*8..+7

    // XCD-aware swizzle (bijective on 784; 392*64 == SP so no batch crossing)
    const int sb  = (blockIdx.x & 7) * 98 + (blockIdx.x >> 3);
    const int s0  = sb * 64;
    const int n   = s0 / SP;
    const int spb = s0 % SP;

    const int sp = spb + wv * 16 + posq;
    const int to = sp / (HH * WW);
    const int hw = sp % (HH * WW);
    const int ho = hw / WW;
    const int wo = hw % WW;

    f32x4 acc[4];
#pragma unroll
    for (int ct = 0; ct < 4; ++ct)
#pragma unroll
        for (int r = 0; r < 4; ++r) acc[ct][r] = 0.f;

    const __half* xn   = xTh + (size_t)n * SP * CIN;
    const float*  offn = off + (size_t)n * (3 * KK) * SP + sp;

#pragma unroll 3
    for (int k = 0; k < KK; ++k) {
        const int kt  = k / 9;
        const int khh = (k / 3) % 3;
        const int kww = k % 3;

        const float pt_ = (float)(to - 1 + kt)  + offn[(k * 3 + 0) * SP];
        const float ph_ = (float)(ho - 1 + khh) + offn[(k * 3 + 1) * SP];
        const float pw_ = (float)(wo - 1 + kww) + offn[(k * 3 + 2) * SP];

        const float ft = floorf(pt_), fh = floorf(ph_), fw = floorf(pw_);
        const float lt = pt_ - ft, lh = ph_ - fh, lw = pw_ - fw;
        const int t0 = (int)ft, h0 = (int)fh, w0 = (int)fw;
        const int t1 = t0 + 1, h1 = h0 + 1, w1 = w0 + 1;

        float awt[2], awh[2], aww[2];
        int   it2[2], ih2[2], iw2[2];
        awt[0] = (t0 >= 0 && t0 < TT) ? (1.f - lt) : 0.f;
        awt[1] = (t1 >= 0 && t1 < TT) ? lt : 0.f;
        it2[0] = min(max(t0, 0), TT - 1);  it2[1] = min(max(t1, 0), TT - 1);
        awh[0] = (h0 >= 0 && h0 < HH) ? (1.f - lh) : 0.f;
        awh[1] = (h1 >= 0 && h1 < HH) ? lh : 0.f;
        ih2[0] = min(max(h0, 0), HH - 1);  ih2[1] = min(max(h1, 0), HH - 1);
        aww[0] = (w0 >= 0 && w0 < WW) ? (1.f - lw) : 0.f;
        aww[1] = (w1 >= 0 && w1 < WW) ? lw : 0.f;
        iw2[0] = min(max(w0, 0), WW - 1);  iw2[1] = min(max(w1, 0), WW - 1);

        int   a[8];
        float cw[8];
#pragma unroll
        for (int ci = 0; ci < 8; ++ci) {
            const int i0 = ci >> 2, i1 = (ci >> 1) & 1, i2 = ci & 1;
            a[ci]  = (it2[i0] * HH + ih2[i1]) * WW + iw2[i2];
            cw[ci] = awt[i0] * awh[i1] * aww[i2];
        }

        // ---- interp -> B-fragment in registers (channels cg*8..+7 of posq)
        // 4 lanes of a position cover one full 64 B xTh line per corner (coalesced)
        float4 g[8];
#pragma unroll
        for (int ci = 0; ci < 8; ++ci)
            g[ci] = *(const float4*)(xn + (size_t)a[ci] * CIN + cg * 8);

        __half2 vacc[4];
#pragma unroll
        for (int j = 0; j < 4; ++j) vacc[j] = __floats2half2_rn(0.f, 0.f);
#pragma unroll
        for (int ci = 0; ci < 8; ++ci) {
            const __half2* uh = (const __half2*)&g[ci];
            const __half2 cw2 = __float2half2_rn(cw[ci]);
            vacc[0] = __hfma2(cw2, uh[0], vacc[0]);
            vacc[1] = __hfma2(cw2, uh[1], vacc[1]);
            vacc[2] = __hfma2(cw2, uh[2], vacc[2]);
            vacc[3] = __hfma2(cw2, uh[3], vacc[3]);
        }
        const half8 bfrag = *(const half8*)vacc;

        // ---- 4 MFMAs: co tiles 0..3, K=32=CIN in one shot
#pragma unroll
        for (int ct = 0; ct < 4; ++ct) {
            const half8 af = *(const half8*)(wf + (((size_t)k * 4 + ct) * 64 + lane) * 8);
            acc[ct] = __builtin_amdgcn_mfma_f32_16x16x32_f16(af, bfrag, acc[ct], 0, 0, 0);
        }
    }

    // epilogue: C/D map (16x16): col=lane&15 (pos), row=(lane>>4)*4+reg (co)
#pragma unroll
    for (int ct = 0; ct < 4; ++ct)
#pragma unroll
        for (int r = 0; r < 4; ++r) {
            const int co = ct * 16 + cg * 4 + r;
            out[((size_t)n * COUT + co) * SP + spb + wv * 16 + posq] =
                acc[ct][r] + bias[co];
        }
}

extern "C" void kernel_launch(void* const* d_in, const int* in_sizes, int n_in,
                              void* d_out, int out_size, void* d_ws, size_t ws_size,
                              hipStream_t stream) {
    const float* x    = (const float*)d_in[0];
    const float* off  = (const float*)d_in[1];
    const float* w    = (const float*)d_in[2];
    const float* bias = (const float*)d_in[3];
    float* out        = (float*)d_out;

    __half* wf  = (__half*)((char*)d_ws + WF_OFF);
    __half* xTh = (__half*)((char*)d_ws + XTH_OFF);

    prep_kernel<<<NBLK + KK, 256, 0, stream>>>(x, w, xTh, wf);
    dconv3d_kernel<<<NBLK, 256, 0, stream>>>(xTh, off, wf, bias, out);
}